// Round 3
// baseline (10639.739 us; speedup 1.0000x reference)
//
#include <hip/hip_runtime.h>
#include <hip/hip_cooperative_groups.h>
#include <stdint.h>

namespace cg = cooperative_groups;

// SpatialGRU on MI355X, round 3. Single cooperative kernel: internal loop over
// the 159 anti-diagonals with grid.sync() between (was 159 launches @ ~37us).
// Block = (cell column rc, batch half bh); 16 waves; wave tile 64n x 64b ->
// acc[4][4]=64 VGPRs, 1024-thread block caps VGPRs at 128 (4 waves/SIMD).
// inputs pre-transposed to xt[cell][b*32+c] bf16 (kills the 16x-overfetch
// stride-25.6KB gather). hz/zi/cw scratch now in LDS (q 54KB + 96KB = 152.5KB).

typedef __bf16 bf16x8 __attribute__((ext_vector_type(8)));
typedef float  f32x4  __attribute__((ext_vector_type(4)));
typedef unsigned short ushort4v __attribute__((ext_vector_type(4)));
typedef unsigned short ushort2v __attribute__((ext_vector_type(2)));

#define QPITCH 424            // 416 q cols + 8 pad (bf16 elems)
#define LDS_BYTES 152576      // 64*424*2 (q) + 3*128*64*4 (hz,zi,cw)

__device__ __forceinline__ unsigned short f2bf(float x) {
  unsigned int u = __builtin_bit_cast(unsigned int, x);
  u = u + 0x7FFFu + ((u >> 16) & 1u);          // round-to-nearest-even
  return (unsigned short)(u >> 16);
}
__device__ __forceinline__ float bf2f(unsigned short h) {
  unsigned int u = ((unsigned int)h) << 16;
  return __builtin_bit_cast(float, u);
}
__device__ __forceinline__ float sigm(float x) {
  x = fminf(fmaxf(x, -30.f), 30.f);
  return 1.f / (1.f + __expf(-x));
}
__device__ __forceinline__ float tanh_fast(float x) {
  x = fminf(fmaxf(x, -15.f), 15.f);
  float e = __expf(2.f * x);
  return (e - 1.f) / (e + 1.f);
}

// ---------------------------------------------------------------------------
// prep: pack fused W' (1024 x 416) and WU' (128 x 384) into MFMA A-fragment
// order: chunk(kb, nt)[lane][8] = W[nt*16 + (lane&15)][kb*32 + (lane>>4)*8 + j].
// n-layout: 0..383 Wr; 384..895 Wz interleaved n=384+4u+gate (softmax group in
// one lane's 4 acc regs); 896..1023 Wij (nonzero only k>=384 -> kb==12).
// WU' k-blocks 0<->1 swapped (hl,ht,hd -> q order ht,hl,hd) so the r*h A2
// build is a pure in-place column RMW in LDS.
// ---------------------------------------------------------------------------
__global__ void prep_kernel(const float* __restrict__ Wr, const float* __restrict__ Wz,
                            const float* __restrict__ Wij, const float* __restrict__ WU,
                            const float* __restrict__ br, const float* __restrict__ bz,
                            const float* __restrict__ bij,
                            unsigned short* __restrict__ wp1, unsigned short* __restrict__ wp2,
                            float* __restrict__ bfused) {
  int blk = blockIdx.x, lane = threadIdx.x;
  if (blk < 832) {                       // 13 kb * 64 ntiles for W'
    int kb = blk >> 6, nt = blk & 63;
    int n = nt * 16 + (lane & 15);
    int kb8 = kb * 32 + (lane >> 4) * 8;
    unsigned short v[8];
#pragma unroll
    for (int j = 0; j < 8; ++j) {
      int k = kb8 + j; float w;
      if (n < 384) w = Wr[n * 416 + k];
      else if (n < 896) { int u = (n - 384) >> 2, g = (n - 384) & 3; w = Wz[(g * 128 + u) * 416 + k]; }
      else { int u = n - 896; w = (k >= 384) ? Wij[u * 32 + (k - 384)] : 0.f; }
      v[j] = f2bf(w);
    }
    ushort4v* dst = (ushort4v*)(wp1 + ((size_t)(kb * 64 + nt) * 64 + lane) * 8);
    dst[0] = (ushort4v){v[0], v[1], v[2], v[3]};
    dst[1] = (ushort4v){v[4], v[5], v[6], v[7]};
  } else if (blk < 832 + 96) {           // 12 kb * 8 ntiles for WU'
    int b2 = blk - 832;
    int kb = b2 >> 3, nt = b2 & 7;
    int n = nt * 16 + (lane & 15);
    int kb8 = kb * 32 + (lane >> 4) * 8;
    unsigned short v[8];
#pragma unroll
    for (int j = 0; j < 8; ++j) {
      int c = kb8 + j;
      int s = (c < 128) ? c + 128 : (c < 256 ? c - 128 : c);  // block swap
      v[j] = f2bf(WU[n * 384 + s]);
    }
    ushort4v* dst = (ushort4v*)(wp2 + ((size_t)(kb * 8 + nt) * 64 + lane) * 8);
    dst[0] = (ushort4v){v[0], v[1], v[2], v[3]};
    dst[1] = (ushort4v){v[4], v[5], v[6], v[7]};
  } else {                               // fused bias (1024 fp32)
#pragma unroll
    for (int i = 0; i < 16; ++i) {
      int n = lane * 16 + i; float v;
      if (n < 384) v = br[n];
      else if (n < 896) { int u = (n - 384) >> 2, g = (n - 384) & 3; v = bz[g * 128 + u]; }
      else v = bij[n - 896];
      bfused[n] = v;
    }
  }
}

// ---------------------------------------------------------------------------
// transpose x[b][c][l][r] (fp32) -> xt[(l*80+r)][b*32+c] (bf16).
// Coalesced float4 reads along r; LDS tile transpose; 128B-chunk writes.
// grid = 80 l * 64 channel-tiles of 64; block 256.
// ---------------------------------------------------------------------------
__global__ __launch_bounds__(256)
void transpose_kernel(const float* __restrict__ x, unsigned short* __restrict__ xt) {
  __shared__ float tile[64 * 81];
  const int l = blockIdx.x >> 6;
  const int ch0 = (blockIdx.x & 63) * 64;
  const int t = threadIdx.x;
  const int c_l = t >> 2, rq = t & 3;
  const float* src = x + (size_t)(ch0 + c_l) * 6400 + l * 80 + rq * 20;
#pragma unroll
  for (int j = 0; j < 5; ++j) {
    float4 v = *(const float4*)(src + j * 4);
    float* dst = tile + c_l * 81 + rq * 20 + j * 4;
    dst[0] = v.x; dst[1] = v.y; dst[2] = v.z; dst[3] = v.w;
  }
  __syncthreads();
#pragma unroll
  for (int j = 0; j < 10; ++j) {
    int idx = j * 256 + t;                 // 2560 = 80 r * 32 ch-pairs
    int r = idx >> 5, cp = idx & 31;
    ushort2v o = (ushort2v){ f2bf(tile[(cp * 2) * 81 + r]),
                             f2bf(tile[(cp * 2 + 1) * 81 + r]) };
    *(ushort2v*)(xt + ((size_t)(l * 80 + r) * 4096 + ch0 + cp * 2)) = o;
  }
}

// ---------------------------------------------------------------------------
// One cell step for block (rc, bh). LDS: q[64][QPITCH] bf16, then hz/zi/cw
// fp32 [u(128)][bl(64)]. Ring: 3 slots of [80 cells][128 b][128 u] fp32.
// ---------------------------------------------------------------------------
__device__ __forceinline__
void cell_body(int d, int rc, int bh, unsigned short* lds,
               const unsigned short* __restrict__ xt, const float* __restrict__ bfused,
               const unsigned short* __restrict__ wp1, const unsigned short* __restrict__ wp2,
               float* __restrict__ ring, float* __restrict__ out) {
  const int l = d - rc;
  const int tid = threadIdx.x;
  const int wave = tid >> 6, lane = tid & 63;
  const int quad = lane >> 4, l15 = lane & 15;
  float* hz_s = (float*)((char*)lds + 54272);
  float* zi_s = hz_s + 8192;
  float* cw_s = zi_s + 8192;

  const bool vt = (l >= 1), vlft = (rc >= 1), vdg = vt && vlft;
  const float* slot1 = ring + (size_t)(((d + 2) % 3) * 80) * 16384;  // diag d-1
  const float* slot2 = ring + (size_t)(((d + 1) % 3) * 80) * 16384;  // diag d-2
  float* slotw = ring + ((size_t)((d % 3) * 80 + rc)) * 16384;
  const float* htopP  = slot1 + (size_t)rc * 16384;
  const float* hleftP = slot1 + (size_t)(rc - 1) * 16384;
  const float* hdiagP = slot2 + (size_t)(rc - 1) * 16384;

  // ---- stage q = [h_top | h_left | h_diag | s_ij] into LDS as bf16 ----
#pragma unroll
  for (int blkI = 0; blkI < 3; ++blkI) {
    const float* src = ((blkI == 0) ? htopP : (blkI == 1 ? hleftP : hdiagP)) + (size_t)bh * 8192;
    const bool valid = (blkI == 0) ? vt : (blkI == 1 ? vlft : vdg);
#pragma unroll
    for (int it = 0; it < 2; ++it) {
      int idx = it * 1024 + tid;                 // 2048 float4 groups
      int b = idx >> 5, c4 = (idx & 31) << 2;
      ushort4v o = (ushort4v){0, 0, 0, 0};
      if (valid) {
        float4 v = *(const float4*)(src + b * 128 + c4);
        o = (ushort4v){f2bf(v.x), f2bf(v.y), f2bf(v.z), f2bf(v.w)};
      }
      *(ushort4v*)(lds + (size_t)b * QPITCH + blkI * 128 + c4) = o;
    }
  }
  {
    const unsigned short* src = xt + (size_t)(l * 80 + rc) * 4096 + bh * 2048;
    int idx = tid * 2;                           // idx = b_local*32 + c
    int b = idx >> 5, c = idx & 31;
    *(ushort2v*)(lds + (size_t)b * QPITCH + 384 + c) = *(const ushort2v*)(src + idx);
  }
  __syncthreads();

  // ---- GEMM1: fused [r|z|wij]^T = W' @ q^T, wave tile 64n x 64b ----
  f32x4 acc[4][4];
#pragma unroll
  for (int mt = 0; mt < 4; ++mt)
#pragma unroll
    for (int bt = 0; bt < 4; ++bt) acc[mt][bt] = (f32x4){0.f, 0.f, 0.f, 0.f};

  const int ntb = wave * 4;
  const int kb0 = (wave >= 14) ? 12 : 0;   // wij rows are zero for k < 384
  for (int kb = kb0; kb < 13; ++kb) {
    bf16x8 wf[4], qf[4];
#pragma unroll
    for (int mt = 0; mt < 4; ++mt)
      wf[mt] = *(const bf16x8*)(wp1 + ((size_t)(kb * 64 + ntb + mt) * 64 + lane) * 8);
#pragma unroll
    for (int bt = 0; bt < 4; ++bt)
      qf[bt] = *(const bf16x8*)(lds + (size_t)(bt * 16 + l15) * QPITCH + kb * 32 + quad * 8);
#pragma unroll
    for (int mt = 0; mt < 4; ++mt)
#pragma unroll
      for (int bt = 0; bt < 4; ++bt)
        acc[mt][bt] = __builtin_amdgcn_mfma_f32_16x16x32_bf16(wf[mt], qf[bt], acc[mt][bt], 0, 0, 0);
  }
  __syncthreads();   // all q reads done before the in-place A2 RMW

  if (wave < 6) {
    // ---- r class: sigmoid, then A2' = r*q in place in LDS.
    // r-col c of hcat=[hl|ht|hd] -> q col: c<128 -> c+128; <256 -> c-128; else c.
    const int rn0 = wave * 64;
    const int shift = (rn0 < 128) ? 128 : (rn0 < 256 ? -128 : 0);
#pragma unroll
    for (int mt = 0; mt < 4; ++mt)
#pragma unroll
      for (int bt = 0; bt < 4; ++bt) {
        int n0 = rn0 + mt * 16 + quad * 4;
        int row = bt * 16 + l15;
        unsigned short* p = lds + (size_t)row * QPITCH + n0 + shift;
        ushort4v qv = *(ushort4v*)p;
        f32x4 bf = *(const f32x4*)(bfused + n0);
        ushort4v o;
#pragma unroll
        for (int g = 0; g < 4; ++g) {
          float r = sigm(acc[mt][bt][g] + bf[g]);
          o[g] = f2bf(bf2f(qv[g]) * r);
        }
        *(ushort4v*)p = o;
      }
  } else if (wave < 14) {
    // ---- z class: lane-local softmax over 4 gates; fold fp32 h's ----
#pragma unroll
    for (int mt = 0; mt < 4; ++mt)
#pragma unroll
      for (int bt = 0; bt < 4; ++bt) {
        int nb = wave * 64 + mt * 16 + quad * 4;
        int u = (nb - 384) >> 2;
        int bl = bt * 16 + l15;
        int bg = bh * 64 + bl;
        f32x4 bf = *(const f32x4*)(bfused + nb);
        float v0 = acc[mt][bt][0] + bf[0];
        float v1 = acc[mt][bt][1] + bf[1];
        float v2 = acc[mt][bt][2] + bf[2];
        float v3 = acc[mt][bt][3] + bf[3];
        float m = fmaxf(fmaxf(v0, v1), fmaxf(v2, v3));
        float e0 = __expf(v0 - m), e1 = __expf(v1 - m);
        float e2 = __expf(v2 - m), e3 = __expf(v3 - m);
        float inv = 1.f / (e0 + e1 + e2 + e3);
        float hl = vlft ? hleftP[bg * 128 + u] : 0.f;
        float ht = vt   ? htopP [bg * 128 + u] : 0.f;
        float hd = vdg  ? hdiagP[bg * 128 + u] : 0.f;
        hz_s[u * 64 + bl] = (e1 * hl + e2 * ht + e3 * hd) * inv;  // zl,zt,zd
        zi_s[u * 64 + bl] = e0 * inv;
      }
  } else {
    // ---- wij class: cw = acc + bij ----
#pragma unroll
    for (int mt = 0; mt < 4; ++mt)
#pragma unroll
      for (int bt = 0; bt < 4; ++bt) {
        int n0 = wave * 64 + mt * 16 + quad * 4;
        int uw = n0 - 896;
        int bl = bt * 16 + l15;
        f32x4 bf = *(const f32x4*)(bfused + n0);
#pragma unroll
        for (int g = 0; g < 4; ++g)
          cw_s[(uw + g) * 64 + bl] = acc[mt][bt][g] + bf[g];
      }
  }
  __syncthreads();

  // ---- GEMM2: hU^T = WU' @ A2'^T (M=128 u, K=384, N=64 bl) ----
  const int m2 = wave >> 1, bsel = wave & 1;
  f32x4 acc2[2];
  acc2[0] = (f32x4){0.f, 0.f, 0.f, 0.f};
  acc2[1] = (f32x4){0.f, 0.f, 0.f, 0.f};
  for (int kb = 0; kb < 12; ++kb) {
    bf16x8 wf = *(const bf16x8*)(wp2 + ((size_t)(kb * 8 + m2) * 64 + lane) * 8);
    bf16x8 q0 = *(const bf16x8*)(lds + (size_t)((bsel * 2 + 0) * 16 + l15) * QPITCH + kb * 32 + quad * 8);
    bf16x8 q1 = *(const bf16x8*)(lds + (size_t)((bsel * 2 + 1) * 16 + l15) * QPITCH + kb * 32 + quad * 8);
    acc2[0] = __builtin_amdgcn_mfma_f32_16x16x32_bf16(wf, q0, acc2[0], 0, 0, 0);
    acc2[1] = __builtin_amdgcn_mfma_f32_16x16x32_bf16(wf, q1, acc2[1], 0, 0, 0);
  }

  // ---- combine: h = hz + zi * tanh(cw + hU); write fp32 ring (+out) ----
#pragma unroll
  for (int bt = 0; bt < 2; ++bt) {
    int bl = (bsel * 2 + bt) * 16 + l15;
    int u0 = m2 * 16 + quad * 4;
    f32x4 h;
#pragma unroll
    for (int g = 0; g < 4; ++g) {
      float cw  = cw_s[(u0 + g) * 64 + bl];
      float hzv = hz_s[(u0 + g) * 64 + bl];
      float ziv = zi_s[(u0 + g) * 64 + bl];
      h[g] = hzv + ziv * tanh_fast(cw + acc2[bt][g]);
    }
    *(f32x4*)(slotw + (size_t)(bh * 64 + bl) * 128 + u0) = h;
    if (d == 158) *(f32x4*)(out + (size_t)(bh * 64 + bl) * 128 + u0) = h;
  }
}

// ---------------------------------------------------------------------------
__global__ __launch_bounds__(1024)
void gru_coop(const unsigned short* __restrict__ xt, const float* __restrict__ bfused,
              const unsigned short* __restrict__ wp1, const unsigned short* __restrict__ wp2,
              float* __restrict__ ring, float* __restrict__ out) {
  cg::grid_group gg = cg::this_grid();
  extern __shared__ unsigned short lds[];
  const int blk = blockIdx.x;
  const int rc = (blk < 80) ? blk : blk - 80;
  const int bh = (blk < 80) ? 0 : 1;
  for (int d = 0; d < 159; ++d) {
    const int l = d - rc;
    if (l >= 0 && l < 80)
      cell_body(d, rc, bh, lds, xt, bfused, wp1, wp2, ring, out);
    gg.sync();
  }
}

// Fallback path (if cooperative launch is rejected): one launch per diagonal.
__global__ __launch_bounds__(1024)
void gru_step(int d, const unsigned short* __restrict__ xt, const float* __restrict__ bfused,
              const unsigned short* __restrict__ wp1, const unsigned short* __restrict__ wp2,
              float* __restrict__ ring, float* __restrict__ out) {
  extern __shared__ unsigned short lds[];
  const int blk = blockIdx.x;
  const int rc = (blk < 80) ? blk : blk - 80;
  const int bh = (blk < 80) ? 0 : 1;
  const int l = d - rc;
  if (l >= 0 && l < 80)
    cell_body(d, rc, bh, lds, xt, bfused, wp1, wp2, ring, out);
}

// ---------------------------------------------------------------------------
extern "C" void kernel_launch(void* const* d_in, const int* in_sizes, int n_in,
                              void* d_out, int out_size, void* d_ws, size_t ws_size,
                              hipStream_t stream) {
  const float* x   = (const float*)d_in[0];
  const float* Wr  = (const float*)d_in[1];
  const float* br  = (const float*)d_in[2];
  const float* Wz  = (const float*)d_in[3];
  const float* bz  = (const float*)d_in[4];
  const float* Wij = (const float*)d_in[5];
  const float* bij = (const float*)d_in[6];
  const float* WU  = (const float*)d_in[7];
  float* out = (float*)d_out;

  // ws layout (~69.1 MB; harness provides ~400 MB)
  char* ws = (char*)d_ws;
  unsigned short* wp1 = (unsigned short*)(ws);                    //    851,968 B
  unsigned short* wp2 = (unsigned short*)(ws + 851968);           //     98,304 B
  float* bfused       = (float*)(ws + 950272);                    //      4,096 B
  float* ring         = (float*)(ws + 954368);                    // 15,728,640 B
  unsigned short* xt  = (unsigned short*)(ws + 954368 + 15728640); // 52,428,800 B

  (void)hipFuncSetAttribute((const void*)gru_coop,
                            hipFuncAttributeMaxDynamicSharedMemorySize, LDS_BYTES);
  (void)hipFuncSetAttribute((const void*)gru_step,
                            hipFuncAttributeMaxDynamicSharedMemorySize, LDS_BYTES);

  prep_kernel<<<929, 64, 0, stream>>>(Wr, Wz, Wij, WU, br, bz, bij, wp1, wp2, bfused);
  transpose_kernel<<<5120, 256, 0, stream>>>(x, xt);

  const unsigned short* xt_c = xt;
  const float* bf_c = bfused;
  const unsigned short* wp1_c = wp1;
  const unsigned short* wp2_c = wp2;
  float* ring_l = ring;
  float* out_l = out;
  void* args[] = {(void*)&xt_c, (void*)&bf_c, (void*)&wp1_c, (void*)&wp2_c,
                  (void*)&ring_l, (void*)&out_l};
  hipError_t e = hipLaunchCooperativeKernel((const void*)gru_coop, dim3(160), dim3(1024),
                                            args, LDS_BYTES, stream);
  if (e != hipSuccess) {
    for (int d = 0; d < 159; ++d)
      gru_step<<<160, 1024, LDS_BYTES, stream>>>(d, xt, bfused, wp1, wp2, ring, out);
  }
}

// Round 4
// 8192.461 us; speedup vs baseline: 1.2987x; 1.2987x over previous
//
#include <hip/hip_runtime.h>
#include <stdint.h>

// SpatialGRU on MI355X, round 4. Persistent cooperative kernel, but with NO
// grid.sync(): round 3 showed cg::sync's agent-scope acq_rel fences write back
// + invalidate every XCD's L2 each diagonal (FETCH 15.8 MB/step — weights
// refetched 159x). Here cross-XCD traffic (the h ring only) uses relaxed
// agent-scope atomics (coherence-point ops, no cache maintenance), and the
// barrier is a relaxed atomic counter: s_waitcnt vmcnt(0) + __syncthreads
// (drain store acks) -> atomicAdd(arr[d]); readers spin arr[d-1]==160.
// L2 is never invalidated -> packed weights stay L2-hot all 159 steps.
// Persistence bonus: h_left of step d IS h_diag of step d+1 -> carried in
// registers (bf16 staging copy + fp32 z-fold copy), halving fabric reads.
// h_top is the block's own previous output -> normal cached loads.

typedef __bf16 bf16x8 __attribute__((ext_vector_type(8)));
typedef float  f32x4  __attribute__((ext_vector_type(4)));
typedef unsigned short ushort4v __attribute__((ext_vector_type(4)));
typedef unsigned short ushort2v __attribute__((ext_vector_type(2)));

#define QPITCH 424            // 416 q cols + 8 pad (bf16 elems)
#define LDS_BYTES 152576      // 64*424*2 (q) + 3*128*64*4 (hz,zi,cw)
#define NBLK 160u

__device__ __forceinline__ unsigned short f2bf(float x) {
  unsigned int u = __builtin_bit_cast(unsigned int, x);
  u = u + 0x7FFFu + ((u >> 16) & 1u);          // round-to-nearest-even
  return (unsigned short)(u >> 16);
}
__device__ __forceinline__ float bf2f(unsigned short h) {
  unsigned int u = ((unsigned int)h) << 16;
  return __builtin_bit_cast(float, u);
}
__device__ __forceinline__ float sigm(float x) {
  x = fminf(fmaxf(x, -30.f), 30.f);
  return 1.f / (1.f + __expf(-x));
}
__device__ __forceinline__ float tanh_fast(float x) {
  x = fminf(fmaxf(x, -15.f), 15.f);
  float e = __expf(2.f * x);
  return (e - 1.f) / (e + 1.f);
}
// Cross-XCD (coherence-point) ops: bypass non-coherent L1/L2, no fences.
__device__ __forceinline__ f32x4 load_remote4(const float* p) {
  f32x4 v;
  v[0] = __hip_atomic_load(p + 0, __ATOMIC_RELAXED, __HIP_MEMORY_SCOPE_AGENT);
  v[1] = __hip_atomic_load(p + 1, __ATOMIC_RELAXED, __HIP_MEMORY_SCOPE_AGENT);
  v[2] = __hip_atomic_load(p + 2, __ATOMIC_RELAXED, __HIP_MEMORY_SCOPE_AGENT);
  v[3] = __hip_atomic_load(p + 3, __ATOMIC_RELAXED, __HIP_MEMORY_SCOPE_AGENT);
  return v;
}
__device__ __forceinline__ void store_remote(float* p, float v) {
  __hip_atomic_store(p, v, __ATOMIC_RELAXED, __HIP_MEMORY_SCOPE_AGENT);
}

// ---------------------------------------------------------------------------
// prep: pack fused W' (1024 x 416) and WU' (128 x 384) into MFMA A-fragment
// order: chunk(kb, nt)[lane][8] = W[nt*16 + (lane&15)][kb*32 + (lane>>4)*8 + j].
// n-layout: 0..383 Wr; 384..895 Wz permuted so a z-lane's 4 tiles (mt) map to
// 4 CONSECUTIVE u (float4 h-fold loads, full 64B fabric lines):
//   n -> tile t=(n-384)>>4, W8=t>>2, mt=t&3, q4=(n>>2)&3, g=n&3,
//   u = W8*16 + q4*4 + mt, source row = g*128+u.
// 896..1023 Wij (nonzero only k>=384 -> kb==12).
// WU' k-blocks 0<->1 swapped (hl,ht,hd -> q order ht,hl,hd) so the r*h A2
// build is a pure in-place column RMW in LDS.
// ---------------------------------------------------------------------------
__global__ void prep_kernel(const float* __restrict__ Wr, const float* __restrict__ Wz,
                            const float* __restrict__ Wij, const float* __restrict__ WU,
                            const float* __restrict__ br, const float* __restrict__ bz,
                            const float* __restrict__ bij,
                            unsigned short* __restrict__ wp1, unsigned short* __restrict__ wp2,
                            float* __restrict__ bfused) {
  int blk = blockIdx.x, lane = threadIdx.x;
  if (blk < 832) {                       // 13 kb * 64 ntiles for W'
    int kb = blk >> 6, nt = blk & 63;
    int n = nt * 16 + (lane & 15);
    int kb8 = kb * 32 + (lane >> 4) * 8;
    unsigned short v[8];
#pragma unroll
    for (int j = 0; j < 8; ++j) {
      int k = kb8 + j; float w;
      if (n < 384) w = Wr[n * 416 + k];
      else if (n < 896) {
        int t = (n - 384) >> 4, W8 = t >> 2, mt = t & 3;
        int q4 = (n >> 2) & 3, g = n & 3;
        int u = W8 * 16 + q4 * 4 + mt;
        w = Wz[(g * 128 + u) * 416 + k];
      } else { int u = n - 896; w = (k >= 384) ? Wij[u * 32 + (k - 384)] : 0.f; }
      v[j] = f2bf(w);
    }
    ushort4v* dst = (ushort4v*)(wp1 + ((size_t)(kb * 64 + nt) * 64 + lane) * 8);
    dst[0] = (ushort4v){v[0], v[1], v[2], v[3]};
    dst[1] = (ushort4v){v[4], v[5], v[6], v[7]};
  } else if (blk < 832 + 96) {           // 12 kb * 8 ntiles for WU'
    int b2 = blk - 832;
    int kb = b2 >> 3, nt = b2 & 7;
    int n = nt * 16 + (lane & 15);
    int kb8 = kb * 32 + (lane >> 4) * 8;
    unsigned short v[8];
#pragma unroll
    for (int j = 0; j < 8; ++j) {
      int c = kb8 + j;
      int s = (c < 128) ? c + 128 : (c < 256 ? c - 128 : c);  // block swap
      v[j] = f2bf(WU[n * 384 + s]);
    }
    ushort4v* dst = (ushort4v*)(wp2 + ((size_t)(kb * 8 + nt) * 64 + lane) * 8);
    dst[0] = (ushort4v){v[0], v[1], v[2], v[3]};
    dst[1] = (ushort4v){v[4], v[5], v[6], v[7]};
  } else {                               // fused bias (1024 fp32)
#pragma unroll
    for (int i = 0; i < 16; ++i) {
      int n = lane * 16 + i; float v;
      if (n < 384) v = br[n];
      else if (n < 896) {
        int t = (n - 384) >> 4, W8 = t >> 2, mt = t & 3;
        int q4 = (n >> 2) & 3, g = n & 3;
        int u = W8 * 16 + q4 * 4 + mt;
        v = bz[g * 128 + u];
      } else v = bij[n - 896];
      bfused[n] = v;
    }
  }
}

// ---------------------------------------------------------------------------
// transpose x[b][c][l][r] (fp32) -> xt[(l*80+r)][b*32+c] (bf16).
// ---------------------------------------------------------------------------
__global__ __launch_bounds__(256)
void transpose_kernel(const float* __restrict__ x, unsigned short* __restrict__ xt) {
  __shared__ float tile[64 * 81];
  const int l = blockIdx.x >> 6;
  const int ch0 = (blockIdx.x & 63) * 64;
  const int t = threadIdx.x;
  const int c_l = t >> 2, rq = t & 3;
  const float* src = x + (size_t)(ch0 + c_l) * 6400 + l * 80 + rq * 20;
#pragma unroll
  for (int j = 0; j < 5; ++j) {
    float4 v = *(const float4*)(src + j * 4);
    float* dst = tile + c_l * 81 + rq * 20 + j * 4;
    dst[0] = v.x; dst[1] = v.y; dst[2] = v.z; dst[3] = v.w;
  }
  __syncthreads();
#pragma unroll
  for (int j = 0; j < 10; ++j) {
    int idx = j * 256 + t;                 // 2560 = 80 r * 32 ch-pairs
    int r = idx >> 5, cp = idx & 31;
    ushort2v o = (ushort2v){ f2bf(tile[(cp * 2) * 81 + r]),
                             f2bf(tile[(cp * 2 + 1) * 81 + r]) };
    *(ushort2v*)(xt + ((size_t)(l * 80 + r) * 4096 + ch0 + cp * 2)) = o;
  }
}

__global__ void zero_arr(unsigned int* a) { a[threadIdx.x] = 0u; }

// ---------------------------------------------------------------------------
// One cell step for block (rc, bh). CARRY: persistent-register reuse of
// h_left(d) as h_diag(d+1) (coop path only; fallback re-reads remotely).
// ---------------------------------------------------------------------------
template<bool CARRY>
__device__ __forceinline__
void cell_body(int d, int rc, int bh, unsigned short* lds,
               const unsigned short* __restrict__ xt, const float* __restrict__ bfused,
               const unsigned short* __restrict__ wp1, const unsigned short* __restrict__ wp2,
               float* __restrict__ ring, float* __restrict__ out,
               ushort4v hl_st[2], f32x4 hl_zf[4]) {
  const int l = d - rc;
  const int tid = threadIdx.x;
  const int wave = tid >> 6, lane = tid & 63;
  const int quad = lane >> 4, l15 = lane & 15;
  float* hz_s = (float*)((char*)lds + 54272);
  float* zi_s = hz_s + 8192;
  float* cw_s = zi_s + 8192;

  const bool vt = (l >= 1), vlft = (rc >= 1), vdg = vt && vlft;
  const float* slot1 = ring + (size_t)(((d + 2) % 3) * 80) * 16384;  // diag d-1
  const float* slot2 = ring + (size_t)(((d + 1) % 3) * 80) * 16384;  // diag d-2
  float* slotw = ring + ((size_t)((d % 3) * 80 + rc)) * 16384;
  const float* htopP  = slot1 + (size_t)rc * 16384;
  const float* hleftP = slot1 + (size_t)(rc - 1) * 16384;
  const float* hdiagP = slot2 + (size_t)(rc - 1) * 16384;

  // ---- stage q = [h_top | h_left | h_diag | s_ij] into LDS as bf16 ----
#pragma unroll
  for (int it = 0; it < 2; ++it) {
    int idx = it * 1024 + tid;                 // 2048 float4 groups
    int b = idx >> 5, c4 = (idx & 31) << 2;
    unsigned short* row = lds + (size_t)b * QPITCH;
    // h_top: own previous output, normal cached loads
    ushort4v ot = (ushort4v){0, 0, 0, 0};
    if (vt) {
      float4 v = *(const float4*)(htopP + bh * 8192 + b * 128 + c4);
      ot = (ushort4v){f2bf(v.x), f2bf(v.y), f2bf(v.z), f2bf(v.w)};
    }
    *(ushort4v*)(row + c4) = ot;
    // h_diag: carried from previous step's h_left (or remote re-read)
    ushort4v od = (ushort4v){0, 0, 0, 0};
    if (vdg) {
      if (CARRY) od = hl_st[it];
      else {
        f32x4 v = load_remote4(hdiagP + bh * 8192 + b * 128 + c4);
        od = (ushort4v){f2bf(v[0]), f2bf(v[1]), f2bf(v[2]), f2bf(v[3])};
      }
    }
    *(ushort4v*)(row + 256 + c4) = od;
    // h_left: remote (other XCD) load; save as next step's h_diag
    ushort4v ol = (ushort4v){0, 0, 0, 0};
    if (vlft) {
      f32x4 v = load_remote4(hleftP + bh * 8192 + b * 128 + c4);
      ol = (ushort4v){f2bf(v[0]), f2bf(v[1]), f2bf(v[2]), f2bf(v[3])};
    }
    *(ushort4v*)(row + 128 + c4) = ol;
    if (CARRY) hl_st[it] = ol;
  }
  {
    const unsigned short* src = xt + (size_t)(l * 80 + rc) * 4096 + bh * 2048;
    int idx = tid * 2;                           // idx = b_local*32 + c
    int b = idx >> 5, c = idx & 31;
    *(ushort2v*)(lds + (size_t)b * QPITCH + 384 + c) = *(const ushort2v*)(src + idx);
  }
  __syncthreads();

  // ---- GEMM1: fused [r|z|wij]^T = W' @ q^T, wave tile 64n x 64b ----
  f32x4 acc[4][4];
#pragma unroll
  for (int mt = 0; mt < 4; ++mt)
#pragma unroll
    for (int bt = 0; bt < 4; ++bt) acc[mt][bt] = (f32x4){0.f, 0.f, 0.f, 0.f};

  const int ntb = wave * 4;
  const int kb0 = (wave >= 14) ? 12 : 0;   // wij rows are zero for k < 384
  for (int kb = kb0; kb < 13; ++kb) {
    bf16x8 wf[4], qf[4];
#pragma unroll
    for (int mt = 0; mt < 4; ++mt)
      wf[mt] = *(const bf16x8*)(wp1 + ((size_t)(kb * 64 + ntb + mt) * 64 + lane) * 8);
#pragma unroll
    for (int bt = 0; bt < 4; ++bt)
      qf[bt] = *(const bf16x8*)(lds + (size_t)(bt * 16 + l15) * QPITCH + kb * 32 + quad * 8);
#pragma unroll
    for (int mt = 0; mt < 4; ++mt)
#pragma unroll
      for (int bt = 0; bt < 4; ++bt)
        acc[mt][bt] = __builtin_amdgcn_mfma_f32_16x16x32_bf16(wf[mt], qf[bt], acc[mt][bt], 0, 0, 0);
  }
  __syncthreads();   // all q reads done before the in-place A2 RMW

  if (wave < 6) {
    // ---- r class: sigmoid, then A2' = r*q in place in LDS ----
    const int rn0 = wave * 64;
    const int shift = (rn0 < 128) ? 128 : (rn0 < 256 ? -128 : 0);
#pragma unroll
    for (int mt = 0; mt < 4; ++mt)
#pragma unroll
      for (int bt = 0; bt < 4; ++bt) {
        int n0 = rn0 + mt * 16 + quad * 4;
        int row = bt * 16 + l15;
        unsigned short* p = lds + (size_t)row * QPITCH + n0 + shift;
        ushort4v qv = *(ushort4v*)p;
        f32x4 bf = *(const f32x4*)(bfused + n0);
        ushort4v o;
#pragma unroll
        for (int g = 0; g < 4; ++g) {
          float r = sigm(acc[mt][bt][g] + bf[g]);
          o[g] = f2bf(bf2f(qv[g]) * r);
        }
        *(ushort4v*)p = o;
      }
  } else if (wave < 14) {
    // ---- z class: softmax + h-fold. Wz permutation puts a lane's 4 tiles at
    // 4 consecutive u -> one float4 per source per bt (full fabric lines).
    const int u4 = (wave - 6) * 16 + quad * 4;
#pragma unroll
    for (int bt = 0; bt < 4; ++bt) {
      int bl = bt * 16 + l15;
      int bg = bh * 64 + bl;
      f32x4 hl4 = (f32x4){0.f, 0.f, 0.f, 0.f};
      f32x4 ht4 = (f32x4){0.f, 0.f, 0.f, 0.f};
      f32x4 hd4 = (f32x4){0.f, 0.f, 0.f, 0.f};
      if (vlft) hl4 = load_remote4(hleftP + (size_t)bg * 128 + u4);
      if (vt)   ht4 = *(const f32x4*)(htopP + (size_t)bg * 128 + u4);
      if (vdg)  hd4 = CARRY ? hl_zf[bt] : load_remote4(hdiagP + (size_t)bg * 128 + u4);
      if (CARRY) hl_zf[bt] = hl4;
#pragma unroll
      for (int mt = 0; mt < 4; ++mt) {
        int nb = wave * 64 + mt * 16 + quad * 4;
        f32x4 bf = *(const f32x4*)(bfused + nb);
        float v0 = acc[mt][bt][0] + bf[0];
        float v1 = acc[mt][bt][1] + bf[1];
        float v2 = acc[mt][bt][2] + bf[2];
        float v3 = acc[mt][bt][3] + bf[3];
        float m = fmaxf(fmaxf(v0, v1), fmaxf(v2, v3));
        float e0 = __expf(v0 - m), e1 = __expf(v1 - m);
        float e2 = __expf(v2 - m), e3 = __expf(v3 - m);
        float inv = 1.f / (e0 + e1 + e2 + e3);
        int u = u4 + mt;
        hz_s[u * 64 + bl] = (e1 * hl4[mt] + e2 * ht4[mt] + e3 * hd4[mt]) * inv;
        zi_s[u * 64 + bl] = e0 * inv;
      }
    }
  } else {
    // ---- wij class: cw = acc + bij ----
#pragma unroll
    for (int mt = 0; mt < 4; ++mt)
#pragma unroll
      for (int bt = 0; bt < 4; ++bt) {
        int n0 = wave * 64 + mt * 16 + quad * 4;
        int uw = n0 - 896;
        int bl = bt * 16 + l15;
        f32x4 bf = *(const f32x4*)(bfused + n0);
#pragma unroll
        for (int g = 0; g < 4; ++g)
          cw_s[(uw + g) * 64 + bl] = acc[mt][bt][g] + bf[g];
      }
  }
  __syncthreads();

  // ---- GEMM2: hU^T = WU' @ A2'^T (M=128 u, K=384, N=64 bl) ----
  const int m2 = wave >> 1, bsel = wave & 1;
  f32x4 acc2[2];
  acc2[0] = (f32x4){0.f, 0.f, 0.f, 0.f};
  acc2[1] = (f32x4){0.f, 0.f, 0.f, 0.f};
  for (int kb = 0; kb < 12; ++kb) {
    bf16x8 wf = *(const bf16x8*)(wp2 + ((size_t)(kb * 8 + m2) * 64 + lane) * 8);
    bf16x8 q0 = *(const bf16x8*)(lds + (size_t)((bsel * 2 + 0) * 16 + l15) * QPITCH + kb * 32 + quad * 8);
    bf16x8 q1 = *(const bf16x8*)(lds + (size_t)((bsel * 2 + 1) * 16 + l15) * QPITCH + kb * 32 + quad * 8);
    acc2[0] = __builtin_amdgcn_mfma_f32_16x16x32_bf16(wf, q0, acc2[0], 0, 0, 0);
    acc2[1] = __builtin_amdgcn_mfma_f32_16x16x32_bf16(wf, q1, acc2[1], 0, 0, 0);
  }

  // ---- combine: h = hz + zi * tanh(cw + hU); remote-store h to ring ----
#pragma unroll
  for (int bt = 0; bt < 2; ++bt) {
    int bl = (bsel * 2 + bt) * 16 + l15;
    int u0 = m2 * 16 + quad * 4;
    f32x4 h;
#pragma unroll
    for (int g = 0; g < 4; ++g) {
      float cw  = cw_s[(u0 + g) * 64 + bl];
      float hzv = hz_s[(u0 + g) * 64 + bl];
      float ziv = zi_s[(u0 + g) * 64 + bl];
      h[g] = hzv + ziv * tanh_fast(cw + acc2[bt][g]);
    }
    float* dst = slotw + (size_t)(bh * 64 + bl) * 128 + u0;
    store_remote(dst + 0, h[0]);
    store_remote(dst + 1, h[1]);
    store_remote(dst + 2, h[2]);
    store_remote(dst + 3, h[3]);
    if (d == 158) *(f32x4*)(out + (size_t)(bh * 64 + bl) * 128 + u0) = h;
  }
}

// ---------------------------------------------------------------------------
__global__ __launch_bounds__(1024)
void gru_coop(const unsigned short* __restrict__ xt, const float* __restrict__ bfused,
              const unsigned short* __restrict__ wp1, const unsigned short* __restrict__ wp2,
              float* __restrict__ ring, float* __restrict__ out,
              unsigned int* __restrict__ arr) {
  extern __shared__ unsigned short lds[];
  const int blk = blockIdx.x;
  const int rc = (blk < 80) ? blk : blk - 80;
  const int bh = (blk < 80) ? 0 : 1;
  const int tid = threadIdx.x;
  ushort4v hl_st[2] = {(ushort4v){0,0,0,0}, (ushort4v){0,0,0,0}};
  f32x4 hl_zf[4];
#pragma unroll
  for (int i = 0; i < 4; ++i) hl_zf[i] = (f32x4){0.f, 0.f, 0.f, 0.f};

  for (int d = 0; d < 159; ++d) {
    if (d > 0) {
      if (tid == 0)
        while (__hip_atomic_load(&arr[d - 1], __ATOMIC_RELAXED, __HIP_MEMORY_SCOPE_AGENT) < NBLK)
          __builtin_amdgcn_s_sleep(1);
      __syncthreads();
    }
    const int l = d - rc;
    if (l >= 0 && l < 80)
      cell_body<true>(d, rc, bh, lds, xt, bfused, wp1, wp2, ring, out, hl_st, hl_zf);
    asm volatile("s_waitcnt vmcnt(0)" ::: "memory");
    __syncthreads();
    if (tid == 0)
      (void)__hip_atomic_fetch_add(&arr[d], 1u, __ATOMIC_RELAXED, __HIP_MEMORY_SCOPE_AGENT);
  }
}

// Fallback (coop launch rejected): one launch per diagonal, no register carry.
__global__ __launch_bounds__(1024)
void gru_step(int d, const unsigned short* __restrict__ xt, const float* __restrict__ bfused,
              const unsigned short* __restrict__ wp1, const unsigned short* __restrict__ wp2,
              float* __restrict__ ring, float* __restrict__ out) {
  extern __shared__ unsigned short lds[];
  const int blk = blockIdx.x;
  const int rc = (blk < 80) ? blk : blk - 80;
  const int bh = (blk < 80) ? 0 : 1;
  const int l = d - rc;
  ushort4v hl_st[2]; f32x4 hl_zf[4];
  if (l >= 0 && l < 80)
    cell_body<false>(d, rc, bh, lds, xt, bfused, wp1, wp2, ring, out, hl_st, hl_zf);
}

// ---------------------------------------------------------------------------
extern "C" void kernel_launch(void* const* d_in, const int* in_sizes, int n_in,
                              void* d_out, int out_size, void* d_ws, size_t ws_size,
                              hipStream_t stream) {
  const float* x   = (const float*)d_in[0];
  const float* Wr  = (const float*)d_in[1];
  const float* br  = (const float*)d_in[2];
  const float* Wz  = (const float*)d_in[3];
  const float* bz  = (const float*)d_in[4];
  const float* Wij = (const float*)d_in[5];
  const float* bij = (const float*)d_in[6];
  const float* WU  = (const float*)d_in[7];
  float* out = (float*)d_out;

  // ws layout (~69.1 MB)
  char* ws = (char*)d_ws;
  unsigned short* wp1 = (unsigned short*)(ws);                     //    851,968 B
  unsigned short* wp2 = (unsigned short*)(ws + 851968);            //     98,304 B
  float* bfused       = (float*)(ws + 950272);                     //      4,096 B
  float* ring         = (float*)(ws + 954368);                     // 15,728,640 B
  unsigned short* xt  = (unsigned short*)(ws + 954368 + 15728640); // 52,428,800 B
  unsigned int* arr   = (unsigned int*)(ws + 954368 + 15728640 + 52428800); // 1,024 B

  (void)hipFuncSetAttribute((const void*)gru_coop,
                            hipFuncAttributeMaxDynamicSharedMemorySize, LDS_BYTES);
  (void)hipFuncSetAttribute((const void*)gru_step,
                            hipFuncAttributeMaxDynamicSharedMemorySize, LDS_BYTES);

  prep_kernel<<<929, 64, 0, stream>>>(Wr, Wz, Wij, WU, br, bz, bij, wp1, wp2, bfused);
  transpose_kernel<<<5120, 256, 0, stream>>>(x, xt);
  zero_arr<<<1, 256, 0, stream>>>(arr);

  const unsigned short* xt_c = xt;
  const float* bf_c = bfused;
  const unsigned short* wp1_c = wp1;
  const unsigned short* wp2_c = wp2;
  float* ring_l = ring;
  float* out_l = out;
  unsigned int* arr_l = arr;
  void* args[] = {(void*)&xt_c, (void*)&bf_c, (void*)&wp1_c, (void*)&wp2_c,
                  (void*)&ring_l, (void*)&out_l, (void*)&arr_l};
  hipError_t e = hipLaunchCooperativeKernel((const void*)gru_coop, dim3(160), dim3(1024),
                                            args, LDS_BYTES, stream);
  if (e != hipSuccess) {
    for (int d = 0; d < 159; ++d)
      gru_step<<<160, 1024, LDS_BYTES, stream>>>(d, xt, bfused, wp1, wp2, ring, out);
  }
}

// Round 5
// 7735.081 us; speedup vs baseline: 1.3755x; 1.0591x over previous
//
#include <hip/hip_runtime.h>
#include <stdint.h>

// SpatialGRU on MI355X, round 5. Persistent kernel, point-to-point sync.
// R4 lesson: a global barrier via one agent-scope atomicAdd line = 160
// serialized far-atomic RMWs + 160 pollers on one IC line + convoy effect
// -> ~50us/step. Here: single-writer monotonic done[blk] flags (plain agent
// stores), consumer spins on <=2 flags; ring depth 8 gives elasticity.
// h_top kept in LDS (h_copy aliased onto dead hz region) - own output never
// round-trips the fabric. h_left loaded once (fp32 stash in dead cw region,
// read by z-fold phase), h_diag fp32 carried in registers from the stash.
// Cross-fabric per block-step: 32KB agent load + 32KB agent store + flags.

typedef __bf16 bf16x8 __attribute__((ext_vector_type(8)));
typedef float  f32x4  __attribute__((ext_vector_type(4)));
typedef unsigned short ushort4v __attribute__((ext_vector_type(4)));
typedef unsigned short ushort2v __attribute__((ext_vector_type(2)));

#define QPITCH 424            // 416 q cols + 8 pad (bf16 elems)
#define LDS_BYTES 152576      // 64*424*2 (q) + 3*32KB (hz/hcopy, zi, cw/stash)
#define RING_D 8

__device__ __forceinline__ unsigned short f2bf(float x) {
  unsigned int u = __builtin_bit_cast(unsigned int, x);
  u = u + 0x7FFFu + ((u >> 16) & 1u);          // round-to-nearest-even
  return (unsigned short)(u >> 16);
}
__device__ __forceinline__ float bf2f(unsigned short h) {
  unsigned int u = ((unsigned int)h) << 16;
  return __builtin_bit_cast(float, u);
}
__device__ __forceinline__ float sigm(float x) {
  x = fminf(fmaxf(x, -30.f), 30.f);
  return 1.f / (1.f + __expf(-x));
}
__device__ __forceinline__ float tanh_fast(float x) {
  x = fminf(fmaxf(x, -15.f), 15.f);
  float e = __expf(2.f * x);
  return (e - 1.f) / (e + 1.f);
}
// Cross-XCD (coherence-point) ops: bypass non-coherent L1/L2, no fences.
__device__ __forceinline__ f32x4 load_remote4(const float* p) {
  f32x4 v;
  v[0] = __hip_atomic_load(p + 0, __ATOMIC_RELAXED, __HIP_MEMORY_SCOPE_AGENT);
  v[1] = __hip_atomic_load(p + 1, __ATOMIC_RELAXED, __HIP_MEMORY_SCOPE_AGENT);
  v[2] = __hip_atomic_load(p + 2, __ATOMIC_RELAXED, __HIP_MEMORY_SCOPE_AGENT);
  v[3] = __hip_atomic_load(p + 3, __ATOMIC_RELAXED, __HIP_MEMORY_SCOPE_AGENT);
  return v;
}
__device__ __forceinline__ void store_remote(float* p, float v) {
  __hip_atomic_store(p, v, __ATOMIC_RELAXED, __HIP_MEMORY_SCOPE_AGENT);
}

// ---------------------------------------------------------------------------
// prep: pack fused W' (1024 x 416) and WU' (128 x 384) into MFMA A-fragment
// order: chunk(kb, nt)[lane][8] = W[nt*16 + (lane&15)][kb*32 + (lane>>4)*8 + j].
// n-layout: 0..383 Wr; 384..895 Wz permuted so a z-lane's 4 tiles (mt) map to
// 4 CONSECUTIVE u (float4 h-fold loads): n -> t=(n-384)>>4, W8=t>>2, mt=t&3,
// q4=(n>>2)&3, g=n&3, u=W8*16+q4*4+mt, src row g*128+u. 896..1023 Wij
// (nonzero only k>=384 -> kb==12). WU' k-blocks 0<->1 swapped so the r*h A2
// build is a pure in-place column RMW in LDS.
// ---------------------------------------------------------------------------
__global__ void prep_kernel(const float* __restrict__ Wr, const float* __restrict__ Wz,
                            const float* __restrict__ Wij, const float* __restrict__ WU,
                            const float* __restrict__ br, const float* __restrict__ bz,
                            const float* __restrict__ bij,
                            unsigned short* __restrict__ wp1, unsigned short* __restrict__ wp2,
                            float* __restrict__ bfused) {
  int blk = blockIdx.x, lane = threadIdx.x;
  if (blk < 832) {                       // 13 kb * 64 ntiles for W'
    int kb = blk >> 6, nt = blk & 63;
    int n = nt * 16 + (lane & 15);
    int kb8 = kb * 32 + (lane >> 4) * 8;
    unsigned short v[8];
#pragma unroll
    for (int j = 0; j < 8; ++j) {
      int k = kb8 + j; float w;
      if (n < 384) w = Wr[n * 416 + k];
      else if (n < 896) {
        int t = (n - 384) >> 4, W8 = t >> 2, mt = t & 3;
        int q4 = (n >> 2) & 3, g = n & 3;
        int u = W8 * 16 + q4 * 4 + mt;
        w = Wz[(g * 128 + u) * 416 + k];
      } else { int u = n - 896; w = (k >= 384) ? Wij[u * 32 + (k - 384)] : 0.f; }
      v[j] = f2bf(w);
    }
    ushort4v* dst = (ushort4v*)(wp1 + ((size_t)(kb * 64 + nt) * 64 + lane) * 8);
    dst[0] = (ushort4v){v[0], v[1], v[2], v[3]};
    dst[1] = (ushort4v){v[4], v[5], v[6], v[7]};
  } else if (blk < 832 + 96) {           // 12 kb * 8 ntiles for WU'
    int b2 = blk - 832;
    int kb = b2 >> 3, nt = b2 & 7;
    int n = nt * 16 + (lane & 15);
    int kb8 = kb * 32 + (lane >> 4) * 8;
    unsigned short v[8];
#pragma unroll
    for (int j = 0; j < 8; ++j) {
      int c = kb8 + j;
      int s = (c < 128) ? c + 128 : (c < 256 ? c - 128 : c);  // block swap
      v[j] = f2bf(WU[n * 384 + s]);
    }
    ushort4v* dst = (ushort4v*)(wp2 + ((size_t)(kb * 8 + nt) * 64 + lane) * 8);
    dst[0] = (ushort4v){v[0], v[1], v[2], v[3]};
    dst[1] = (ushort4v){v[4], v[5], v[6], v[7]};
  } else {                               // fused bias (1024 fp32)
#pragma unroll
    for (int i = 0; i < 16; ++i) {
      int n = lane * 16 + i; float v;
      if (n < 384) v = br[n];
      else if (n < 896) {
        int t = (n - 384) >> 4, W8 = t >> 2, mt = t & 3;
        int q4 = (n >> 2) & 3, g = n & 3;
        int u = W8 * 16 + q4 * 4 + mt;
        v = bz[g * 128 + u];
      } else v = bij[n - 896];
      bfused[n] = v;
    }
  }
}

// ---------------------------------------------------------------------------
// transpose x[b][c][l][r] (fp32) -> xt[(l*80+r)][b*32+c] (bf16).
// ---------------------------------------------------------------------------
__global__ __launch_bounds__(256)
void transpose_kernel(const float* __restrict__ x, unsigned short* __restrict__ xt) {
  __shared__ float tile[64 * 81];
  const int l = blockIdx.x >> 6;
  const int ch0 = (blockIdx.x & 63) * 64;
  const int t = threadIdx.x;
  const int c_l = t >> 2, rq = t & 3;
  const float* src = x + (size_t)(ch0 + c_l) * 6400 + l * 80 + rq * 20;
#pragma unroll
  for (int j = 0; j < 5; ++j) {
    float4 v = *(const float4*)(src + j * 4);
    float* dst = tile + c_l * 81 + rq * 20 + j * 4;
    dst[0] = v.x; dst[1] = v.y; dst[2] = v.z; dst[3] = v.w;
  }
  __syncthreads();
#pragma unroll
  for (int j = 0; j < 10; ++j) {
    int idx = j * 256 + t;                 // 2560 = 80 r * 32 ch-pairs
    int r = idx >> 5, cp = idx & 31;
    ushort2v o = (ushort2v){ f2bf(tile[(cp * 2) * 81 + r]),
                             f2bf(tile[(cp * 2 + 1) * 81 + r]) };
    *(ushort2v*)(xt + ((size_t)(l * 80 + r) * 4096 + ch0 + cp * 2)) = o;
  }
}

__global__ void zero_arr(unsigned int* a) { a[threadIdx.x] = 0u; }

// ---------------------------------------------------------------------------
// One cell step. PERSIST: h_top from LDS h_copy, hl stashed in LDS, h_diag
// register-carried, agent ops for cross-block ring traffic. !PERSIST
// (fallback, separate launches): everything from ring via normal loads.
// LDS map: q bf16 [64][QPITCH] @0; R1 @54272 (h_copy [b][u] -> hz_s [u][bl]);
// R2 @+32KB (zi_s [u][bl]); R3 @+64KB (hl stash [b][u] -> cw_s [u][bl]).
// ---------------------------------------------------------------------------
template<bool PERSIST>
__device__ __forceinline__
void cell_body(int d, int rc, int bh, unsigned short* lds,
               const unsigned short* __restrict__ xt, const float* __restrict__ bfused,
               const unsigned short* __restrict__ wp1, const unsigned short* __restrict__ wp2,
               float* __restrict__ ring, float* __restrict__ out,
               ushort4v hl_st[2], f32x4 hl_zf[4]) {
  const int l = d - rc;
  const int tid = threadIdx.x;
  const int wave = tid >> 6, lane = tid & 63;
  const int quad = lane >> 4, l15 = lane & 15;
  float* R1 = (float*)((char*)lds + 54272);   // h_copy, then hz_s
  float* R2 = R1 + 8192;                      // zi_s
  float* R3 = R2 + 8192;                      // hl stash, then cw_s

  const bool vt = (l >= 1), vlft = (rc >= 1), vdg = vt && vlft;
  const float* slot1 = ring + (size_t)(((d + RING_D - 1) % RING_D) * 80) * 16384; // d-1
  const float* slot2 = ring + (size_t)(((d + RING_D - 2) % RING_D) * 80) * 16384; // d-2
  float* slotw = ring + ((size_t)((d % RING_D) * 80 + rc)) * 16384;
  const float* htopP  = slot1 + (size_t)rc * 16384;
  const float* hleftP = slot1 + (size_t)(rc - 1) * 16384;
  const float* hdiagP = slot2 + (size_t)(rc - 1) * 16384;

  // ---- stage q = [h_top | h_left | h_diag | s_ij] into LDS as bf16 ----
#pragma unroll
  for (int it = 0; it < 2; ++it) {
    int idx = it * 1024 + tid;                 // 2048 float4 groups
    int b = idx >> 5, c4 = (idx & 31) << 2;
    unsigned short* row = lds + (size_t)b * QPITCH;
    // h_top
    ushort4v ot = (ushort4v){0, 0, 0, 0};
    if (vt) {
      f32x4 v;
      if (PERSIST) v = *(const f32x4*)(R1 + b * 128 + c4);          // h_copy (LDS)
      else { float4 t4 = *(const float4*)(htopP + bh * 8192 + b * 128 + c4);
             v = (f32x4){t4.x, t4.y, t4.z, t4.w}; }
      ot = (ushort4v){f2bf(v[0]), f2bf(v[1]), f2bf(v[2]), f2bf(v[3])};
    }
    *(ushort4v*)(row + c4) = ot;
    // h_diag
    ushort4v od = (ushort4v){0, 0, 0, 0};
    if (vdg) {
      if (PERSIST) od = hl_st[it];
      else {
        float4 v = *(const float4*)(hdiagP + bh * 8192 + b * 128 + c4);
        od = (ushort4v){f2bf(v.x), f2bf(v.y), f2bf(v.z), f2bf(v.w)};
      }
    }
    *(ushort4v*)(row + 256 + c4) = od;
    // h_left (agent load in PERSIST) + fp32 stash
    ushort4v ol = (ushort4v){0, 0, 0, 0};
    if (vlft) {
      f32x4 v;
      if (PERSIST) v = load_remote4(hleftP + bh * 8192 + b * 128 + c4);
      else { float4 t4 = *(const float4*)(hleftP + bh * 8192 + b * 128 + c4);
             v = (f32x4){t4.x, t4.y, t4.z, t4.w}; }
      ol = (ushort4v){f2bf(v[0]), f2bf(v[1]), f2bf(v[2]), f2bf(v[3])};
      if (PERSIST) *(f32x4*)(R3 + b * 128 + c4) = v;
    }
    *(ushort4v*)(row + 128 + c4) = ol;
    if (PERSIST) hl_st[it] = ol;
  }
  {
    const unsigned short* src = xt + (size_t)(l * 80 + rc) * 4096 + bh * 2048;
    int idx = tid * 2;                           // idx = b_local*32 + c
    int b = idx >> 5, c = idx & 31;
    *(ushort2v*)(lds + (size_t)b * QPITCH + 384 + c) = *(const ushort2v*)(src + idx);
  }
  __syncthreads();                                             // S2

  // ---- GEMM1: fused [r|z|wij]^T = W' @ q^T, wave tile 64n x 64b ----
  f32x4 acc[4][4];
#pragma unroll
  for (int mt = 0; mt < 4; ++mt)
#pragma unroll
    for (int bt = 0; bt < 4; ++bt) acc[mt][bt] = (f32x4){0.f, 0.f, 0.f, 0.f};

  const int ntb = wave * 4;
  const int kb0 = (wave >= 14) ? 12 : 0;   // wij rows are zero for k < 384
  for (int kb = kb0; kb < 13; ++kb) {
    bf16x8 wf[4], qf[4];
#pragma unroll
    for (int mt = 0; mt < 4; ++mt)
      wf[mt] = *(const bf16x8*)(wp1 + ((size_t)(kb * 64 + ntb + mt) * 64 + lane) * 8);
#pragma unroll
    for (int bt = 0; bt < 4; ++bt)
      qf[bt] = *(const bf16x8*)(lds + (size_t)(bt * 16 + l15) * QPITCH + kb * 32 + quad * 8);
#pragma unroll
    for (int mt = 0; mt < 4; ++mt)
#pragma unroll
      for (int bt = 0; bt < 4; ++bt)
        acc[mt][bt] = __builtin_amdgcn_mfma_f32_16x16x32_bf16(wf[mt], qf[bt], acc[mt][bt], 0, 0, 0);
  }
  __syncthreads();                                             // S3

  // ---- phase 1: z waves read hl stash + h_top copy into regs (before the
  // epilogue overwrites those LDS regions); r class does its q RMW here too.
  const int u4 = (wave >= 6 && wave < 14) ? (wave - 6) * 16 + quad * 4 : 0;
  f32x4 hl4s[4], ht4s[4];
  if (wave >= 6 && wave < 14) {
#pragma unroll
    for (int bt = 0; bt < 4; ++bt) {
      int bl = bt * 16 + l15;
      hl4s[bt] = (f32x4){0.f, 0.f, 0.f, 0.f};
      ht4s[bt] = (f32x4){0.f, 0.f, 0.f, 0.f};
      if (PERSIST) {
        if (vlft) hl4s[bt] = *(const f32x4*)(R3 + bl * 128 + u4);
        if (vt)   ht4s[bt] = *(const f32x4*)(R1 + bl * 128 + u4);
      } else {
        int bg = bh * 64 + bl;
        if (vlft) { float4 v = *(const float4*)(hleftP + (size_t)bg * 128 + u4);
                    hl4s[bt] = (f32x4){v.x, v.y, v.z, v.w}; }
        if (vt)   { float4 v = *(const float4*)(htopP + (size_t)bg * 128 + u4);
                    ht4s[bt] = (f32x4){v.x, v.y, v.z, v.w}; }
      }
    }
  }
  if (wave < 6) {
    // ---- r class: sigmoid, then A2' = r*q in place in LDS ----
    const int rn0 = wave * 64;
    const int shift = (rn0 < 128) ? 128 : (rn0 < 256 ? -128 : 0);
#pragma unroll
    for (int mt = 0; mt < 4; ++mt)
#pragma unroll
      for (int bt = 0; bt < 4; ++bt) {
        int n0 = rn0 + mt * 16 + quad * 4;
        int row = bt * 16 + l15;
        unsigned short* p = lds + (size_t)row * QPITCH + n0 + shift;
        ushort4v qv = *(ushort4v*)p;
        f32x4 bf = *(const f32x4*)(bfused + n0);
        ushort4v o;
#pragma unroll
        for (int g = 0; g < 4; ++g) {
          float r = sigm(acc[mt][bt][g] + bf[g]);
          o[g] = f2bf(bf2f(qv[g]) * r);
        }
        *(ushort4v*)p = o;
      }
  }
  __syncthreads();                                             // S4

  // ---- phase 2 epilogue writes ----
  if (wave >= 6 && wave < 14) {
    // z class: lane-local softmax over 4 gates; fold h's
#pragma unroll
    for (int bt = 0; bt < 4; ++bt) {
      int bl = bt * 16 + l15;
      f32x4 hd4 = (f32x4){0.f, 0.f, 0.f, 0.f};
      if (vdg) {
        if (PERSIST) hd4 = hl_zf[bt];
        else { int bg = bh * 64 + bl;
               float4 v = *(const float4*)(hdiagP + (size_t)bg * 128 + u4);
               hd4 = (f32x4){v.x, v.y, v.z, v.w}; }
      }
      if (PERSIST) hl_zf[bt] = hl4s[bt];
#pragma unroll
      for (int mt = 0; mt < 4; ++mt) {
        int nb = wave * 64 + mt * 16 + quad * 4;
        f32x4 bf = *(const f32x4*)(bfused + nb);
        float v0 = acc[mt][bt][0] + bf[0];
        float v1 = acc[mt][bt][1] + bf[1];
        float v2 = acc[mt][bt][2] + bf[2];
        float v3 = acc[mt][bt][3] + bf[3];
        float m = fmaxf(fmaxf(v0, v1), fmaxf(v2, v3));
        float e0 = __expf(v0 - m), e1 = __expf(v1 - m);
        float e2 = __expf(v2 - m), e3 = __expf(v3 - m);
        float inv = 1.f / (e0 + e1 + e2 + e3);
        int u = u4 + mt;
        R1[u * 64 + bl] = (e1 * hl4s[bt][mt] + e2 * ht4s[bt][mt] + e3 * hd4[mt]) * inv;
        R2[u * 64 + bl] = e0 * inv;
      }
    }
  } else if (wave >= 14) {
    // wij class: cw = acc + bij
#pragma unroll
    for (int mt = 0; mt < 4; ++mt)
#pragma unroll
      for (int bt = 0; bt < 4; ++bt) {
        int n0 = wave * 64 + mt * 16 + quad * 4;
        int uw = n0 - 896;
        int bl = bt * 16 + l15;
        f32x4 bf = *(const f32x4*)(bfused + n0);
#pragma unroll
        for (int g = 0; g < 4; ++g)
          R3[(uw + g) * 64 + bl] = acc[mt][bt][g] + bf[g];
      }
  }
  __syncthreads();                                             // S5

  // ---- GEMM2: hU^T = WU' @ A2'^T (M=128 u, K=384, N=64 bl) ----
  const int m2 = wave >> 1, bsel = wave & 1;
  f32x4 acc2[2];
  acc2[0] = (f32x4){0.f, 0.f, 0.f, 0.f};
  acc2[1] = (f32x4){0.f, 0.f, 0.f, 0.f};
  for (int kb = 0; kb < 12; ++kb) {
    bf16x8 wf = *(const bf16x8*)(wp2 + ((size_t)(kb * 8 + m2) * 64 + lane) * 8);
    bf16x8 q0 = *(const bf16x8*)(lds + (size_t)((bsel * 2 + 0) * 16 + l15) * QPITCH + kb * 32 + quad * 8);
    bf16x8 q1 = *(const bf16x8*)(lds + (size_t)((bsel * 2 + 1) * 16 + l15) * QPITCH + kb * 32 + quad * 8);
    acc2[0] = __builtin_amdgcn_mfma_f32_16x16x32_bf16(wf, q0, acc2[0], 0, 0, 0);
    acc2[1] = __builtin_amdgcn_mfma_f32_16x16x32_bf16(wf, q1, acc2[1], 0, 0, 0);
  }

  // ---- combine: h = hz + zi * tanh(cw + hU) ----
  f32x4 hout[2];
#pragma unroll
  for (int bt = 0; bt < 2; ++bt) {
    int bl = (bsel * 2 + bt) * 16 + l15;
    int u0 = m2 * 16 + quad * 4;
#pragma unroll
    for (int g = 0; g < 4; ++g) {
      float cw  = R3[(u0 + g) * 64 + bl];
      float hzv = R1[(u0 + g) * 64 + bl];
      float ziv = R2[(u0 + g) * 64 + bl];
      hout[bt][g] = hzv + ziv * tanh_fast(cw + acc2[bt][g]);
    }
  }
  __syncthreads();                                             // S6
#pragma unroll
  for (int bt = 0; bt < 2; ++bt) {
    int bl = (bsel * 2 + bt) * 16 + l15;
    int u0 = m2 * 16 + quad * 4;
    if (PERSIST) *(f32x4*)(R1 + bl * 128 + u0) = hout[bt];     // h_copy for next step
    float* dst = slotw + (size_t)(bh * 64 + bl) * 128 + u0;
    if (PERSIST) {
      store_remote(dst + 0, hout[bt][0]);
      store_remote(dst + 1, hout[bt][1]);
      store_remote(dst + 2, hout[bt][2]);
      store_remote(dst + 3, hout[bt][3]);
    } else {
      *(f32x4*)dst = hout[bt];
    }
    if (d == 158) *(f32x4*)(out + (size_t)(bh * 64 + bl) * 128 + u0) = hout[bt];
  }
}

// ---------------------------------------------------------------------------
__global__ __launch_bounds__(1024)
void gru_coop(const unsigned short* __restrict__ xt, const float* __restrict__ bfused,
              const unsigned short* __restrict__ wp1, const unsigned short* __restrict__ wp2,
              float* __restrict__ ring, float* __restrict__ out,
              unsigned int* __restrict__ done) {
  extern __shared__ unsigned short lds[];
  const int blk = blockIdx.x;
  const int rc = (blk < 80) ? blk : blk - 80;
  const int bh = (blk < 80) ? 0 : 1;
  const int tid = threadIdx.x;
  ushort4v hl_st[2] = {(ushort4v){0,0,0,0}, (ushort4v){0,0,0,0}};
  f32x4 hl_zf[4];
#pragma unroll
  for (int i = 0; i < 4; ++i) hl_zf[i] = (f32x4){0.f, 0.f, 0.f, 0.f};

  for (int d = 0; d < 159; ++d) {
    const int l = d - rc;
    const bool active = (l >= 0 && l < 80);
    if (active && d > 0 && tid == 0) {
      // data dep: left neighbor finished step d-1
      if (rc >= 1)
        while ((int)__hip_atomic_load(&done[blk - 1], __ATOMIC_RELAXED,
                                      __HIP_MEMORY_SCOPE_AGENT) < d)
          __builtin_amdgcn_s_sleep(1);
      // ring-slot reuse: right neighbor past step d-(RING_D-2)
      if (rc <= 78) {
        int need = d - (RING_D - 2);
        if (need > 0)
          while ((int)__hip_atomic_load(&done[blk + 1], __ATOMIC_RELAXED,
                                        __HIP_MEMORY_SCOPE_AGENT) < need)
            __builtin_amdgcn_s_sleep(1);
      }
    }
    __syncthreads();                                           // S1
    if (active)
      cell_body<true>(d, rc, bh, lds, xt, bfused, wp1, wp2, ring, out, hl_st, hl_zf);
    asm volatile("s_waitcnt vmcnt(0)" ::: "memory");
    __syncthreads();                                           // S7
    if (tid == 0)
      __hip_atomic_store(&done[blk], (unsigned)(d + 1), __ATOMIC_RELAXED,
                         __HIP_MEMORY_SCOPE_AGENT);
  }
}

// Fallback (coop launch rejected): one launch per diagonal, ring mode.
__global__ __launch_bounds__(1024)
void gru_step(int d, const unsigned short* __restrict__ xt, const float* __restrict__ bfused,
              const unsigned short* __restrict__ wp1, const unsigned short* __restrict__ wp2,
              float* __restrict__ ring, float* __restrict__ out) {
  extern __shared__ unsigned short lds[];
  const int blk = blockIdx.x;
  const int rc = (blk < 80) ? blk : blk - 80;
  const int bh = (blk < 80) ? 0 : 1;
  const int l = d - rc;
  ushort4v hl_st[2]; f32x4 hl_zf[4];
  if (l >= 0 && l < 80)
    cell_body<false>(d, rc, bh, lds, xt, bfused, wp1, wp2, ring, out, hl_st, hl_zf);
}

// ---------------------------------------------------------------------------
extern "C" void kernel_launch(void* const* d_in, const int* in_sizes, int n_in,
                              void* d_out, int out_size, void* d_ws, size_t ws_size,
                              hipStream_t stream) {
  const float* x   = (const float*)d_in[0];
  const float* Wr  = (const float*)d_in[1];
  const float* br  = (const float*)d_in[2];
  const float* Wz  = (const float*)d_in[3];
  const float* bz  = (const float*)d_in[4];
  const float* Wij = (const float*)d_in[5];
  const float* bij = (const float*)d_in[6];
  const float* WU  = (const float*)d_in[7];
  float* out = (float*)d_out;

  // ws layout (~95.3 MB)
  char* ws = (char*)d_ws;
  unsigned short* wp1 = (unsigned short*)(ws);                  //    851,968 B
  unsigned short* wp2 = (unsigned short*)(ws + 851968);         //     98,304 B
  float* bfused       = (float*)(ws + 950272);                  //      4,096 B
  float* ring         = (float*)(ws + 954368);                  // 41,943,040 B (8 slots)
  unsigned short* xt  = (unsigned short*)(ws + 42897408);       // 52,428,800 B
  unsigned int* done  = (unsigned int*)(ws + 95326208);         //      1,024 B

  (void)hipFuncSetAttribute((const void*)gru_coop,
                            hipFuncAttributeMaxDynamicSharedMemorySize, LDS_BYTES);
  (void)hipFuncSetAttribute((const void*)gru_step,
                            hipFuncAttributeMaxDynamicSharedMemorySize, LDS_BYTES);

  prep_kernel<<<929, 64, 0, stream>>>(Wr, Wz, Wij, WU, br, bz, bij, wp1, wp2, bfused);
  transpose_kernel<<<5120, 256, 0, stream>>>(x, xt);
  zero_arr<<<1, 256, 0, stream>>>(done);

  const unsigned short* xt_c = xt;
  const float* bf_c = bfused;
  const unsigned short* wp1_c = wp1;
  const unsigned short* wp2_c = wp2;
  float* ring_l = ring;
  float* out_l = out;
  unsigned int* done_l = done;
  void* args[] = {(void*)&xt_c, (void*)&bf_c, (void*)&wp1_c, (void*)&wp2_c,
                  (void*)&ring_l, (void*)&out_l, (void*)&done_l};
  hipError_t e = hipLaunchCooperativeKernel((const void*)gru_coop, dim3(160), dim3(1024),
                                            args, LDS_BYTES, stream);
  if (e != hipSuccess) {
    for (int d = 0; d < 159; ++d)
      gru_step<<<160, 1024, LDS_BYTES, stream>>>(d, xt, bfused, wp1, wp2, ring, out);
  }
}

// Round 6
// 7542.999 us; speedup vs baseline: 1.4105x; 1.0255x over previous
//
#include <hip/hip_runtime.h>
#include <stdint.h>

// SpatialGRU on MI355X, round 6. Persistent kernel, p2p flags (R5) but with
// fabric traffic VECTORIZED: R5's per-dword agent atomics = ~16K IC
// transactions per block-step (plus ~45M poll reads) serialized the fabric
// (~35us/step of wait at only 3.7% MfmaUtil). Here the h handoff uses
// inline-asm global_{load,store}_dwordx4 sc0 sc1 (IC-coherent, 4x fewer
// transactions, coalescable), hl load latency is overlapped with ht/hd/x
// staging, polling backs off, and the stride-128 LDS layouts are padded to
// 132 to kill the 16-way bank conflicts (1.33e8 conflict cycles in R5).

typedef __bf16 bf16x8 __attribute__((ext_vector_type(8)));
typedef float  f32x4  __attribute__((ext_vector_type(4)));
typedef unsigned short ushort4v __attribute__((ext_vector_type(4)));
typedef unsigned short ushort2v __attribute__((ext_vector_type(2)));

#define QPITCH 424            // 416 q cols + 8 pad (bf16 elems)
#define HPITCH 132            // fp32 h_copy/stash row stride (bank spread)
#define LDS_BYTES 154624      // 54272 (q) + 33792 (R1) + 32768 (R2) + 33792 (R3)
#define RING_D 8

__device__ __forceinline__ unsigned short f2bf(float x) {
  unsigned int u = __builtin_bit_cast(unsigned int, x);
  u = u + 0x7FFFu + ((u >> 16) & 1u);          // round-to-nearest-even
  return (unsigned short)(u >> 16);
}
__device__ __forceinline__ float bf2f(unsigned short h) {
  unsigned int u = ((unsigned int)h) << 16;
  return __builtin_bit_cast(float, u);
}
__device__ __forceinline__ float sigm(float x) {
  x = fminf(fmaxf(x, -30.f), 30.f);
  return 1.f / (1.f + __expf(-x));
}
__device__ __forceinline__ float tanh_fast(float x) {
  x = fminf(fmaxf(x, -15.f), 15.f);
  float e = __expf(2.f * x);
  return (e - 1.f) / (e + 1.f);
}
// IC-coherent (bypass L1+L2) vector ops. sc0 sc1 = scope-escalated to the
// chip coherence point; x4 keeps the fabric request count 4x lower than the
// per-dword atomics the compiler emits for agent-scope atomics.
__device__ __forceinline__ void ic_load4_issue(const float* p, f32x4& v) {
  asm volatile("global_load_dwordx4 %0, %1, off sc0 sc1"
               : "=v"(v) : "v"(p) : "memory");
}
__device__ __forceinline__ void ic_wait2(f32x4& a, f32x4& b) {
  asm volatile("s_waitcnt vmcnt(0)" : "+v"(a), "+v"(b) :: "memory");
}
__device__ __forceinline__ void ic_store4(float* p, f32x4 v) {
  asm volatile("global_store_dwordx4 %0, %1, off sc0 sc1"
               :: "v"(p), "v"(v) : "memory");
}

// ---------------------------------------------------------------------------
// prep: pack fused W' (1024 x 416) and WU' (128 x 384) into MFMA A-fragment
// order: chunk(kb, nt)[lane][8] = W[nt*16 + (lane&15)][kb*32 + (lane>>4)*8 + j].
// n-layout: 0..383 Wr; 384..895 Wz permuted so a z-lane's 4 tiles (mt) map to
// 4 CONSECUTIVE u (float4 h-fold loads): n -> t=(n-384)>>4, W8=t>>2, mt=t&3,
// q4=(n>>2)&3, g=n&3, u=W8*16+q4*4+mt, src row g*128+u. 896..1023 Wij
// (nonzero only k>=384 -> kb==12). WU' k-blocks 0<->1 swapped so the r*h A2
// build is a pure in-place column RMW in LDS.
// ---------------------------------------------------------------------------
__global__ void prep_kernel(const float* __restrict__ Wr, const float* __restrict__ Wz,
                            const float* __restrict__ Wij, const float* __restrict__ WU,
                            const float* __restrict__ br, const float* __restrict__ bz,
                            const float* __restrict__ bij,
                            unsigned short* __restrict__ wp1, unsigned short* __restrict__ wp2,
                            float* __restrict__ bfused) {
  int blk = blockIdx.x, lane = threadIdx.x;
  if (blk < 832) {                       // 13 kb * 64 ntiles for W'
    int kb = blk >> 6, nt = blk & 63;
    int n = nt * 16 + (lane & 15);
    int kb8 = kb * 32 + (lane >> 4) * 8;
    unsigned short v[8];
#pragma unroll
    for (int j = 0; j < 8; ++j) {
      int k = kb8 + j; float w;
      if (n < 384) w = Wr[n * 416 + k];
      else if (n < 896) {
        int t = (n - 384) >> 4, W8 = t >> 2, mt = t & 3;
        int q4 = (n >> 2) & 3, g = n & 3;
        int u = W8 * 16 + q4 * 4 + mt;
        w = Wz[(g * 128 + u) * 416 + k];
      } else { int u = n - 896; w = (k >= 384) ? Wij[u * 32 + (k - 384)] : 0.f; }
      v[j] = f2bf(w);
    }
    ushort4v* dst = (ushort4v*)(wp1 + ((size_t)(kb * 64 + nt) * 64 + lane) * 8);
    dst[0] = (ushort4v){v[0], v[1], v[2], v[3]};
    dst[1] = (ushort4v){v[4], v[5], v[6], v[7]};
  } else if (blk < 832 + 96) {           // 12 kb * 8 ntiles for WU'
    int b2 = blk - 832;
    int kb = b2 >> 3, nt = b2 & 7;
    int n = nt * 16 + (lane & 15);
    int kb8 = kb * 32 + (lane >> 4) * 8;
    unsigned short v[8];
#pragma unroll
    for (int j = 0; j < 8; ++j) {
      int c = kb8 + j;
      int s = (c < 128) ? c + 128 : (c < 256 ? c - 128 : c);  // block swap
      v[j] = f2bf(WU[n * 384 + s]);
    }
    ushort4v* dst = (ushort4v*)(wp2 + ((size_t)(kb * 8 + nt) * 64 + lane) * 8);
    dst[0] = (ushort4v){v[0], v[1], v[2], v[3]};
    dst[1] = (ushort4v){v[4], v[5], v[6], v[7]};
  } else {                               // fused bias (1024 fp32)
#pragma unroll
    for (int i = 0; i < 16; ++i) {
      int n = lane * 16 + i; float v;
      if (n < 384) v = br[n];
      else if (n < 896) {
        int t = (n - 384) >> 4, W8 = t >> 2, mt = t & 3;
        int q4 = (n >> 2) & 3, g = n & 3;
        int u = W8 * 16 + q4 * 4 + mt;
        v = bz[g * 128 + u];
      } else v = bij[n - 896];
      bfused[n] = v;
    }
  }
}

// ---------------------------------------------------------------------------
// transpose x[b][c][l][r] (fp32) -> xt[(l*80+r)][b*32+c] (bf16).
// ---------------------------------------------------------------------------
__global__ __launch_bounds__(256)
void transpose_kernel(const float* __restrict__ x, unsigned short* __restrict__ xt) {
  __shared__ float tile[64 * 81];
  const int l = blockIdx.x >> 6;
  const int ch0 = (blockIdx.x & 63) * 64;
  const int t = threadIdx.x;
  const int c_l = t >> 2, rq = t & 3;
  const float* src = x + (size_t)(ch0 + c_l) * 6400 + l * 80 + rq * 20;
#pragma unroll
  for (int j = 0; j < 5; ++j) {
    float4 v = *(const float4*)(src + j * 4);
    float* dst = tile + c_l * 81 + rq * 20 + j * 4;
    dst[0] = v.x; dst[1] = v.y; dst[2] = v.z; dst[3] = v.w;
  }
  __syncthreads();
#pragma unroll
  for (int j = 0; j < 10; ++j) {
    int idx = j * 256 + t;                 // 2560 = 80 r * 32 ch-pairs
    int r = idx >> 5, cp = idx & 31;
    ushort2v o = (ushort2v){ f2bf(tile[(cp * 2) * 81 + r]),
                             f2bf(tile[(cp * 2 + 1) * 81 + r]) };
    *(ushort2v*)(xt + ((size_t)(l * 80 + r) * 4096 + ch0 + cp * 2)) = o;
  }
}

__global__ void zero_arr(unsigned int* a) { a[threadIdx.x] = 0u; }

// ---------------------------------------------------------------------------
// One cell step. PERSIST: h_top from LDS h_copy, hl stashed in LDS, h_diag
// register-carried, IC vector ops for cross-block ring traffic. !PERSIST
// (fallback, separate launches): everything from ring via normal loads.
// LDS map: q bf16 [64][QPITCH] @0; R1 @54272: h_copy [b][HPITCH] / hz [u][64];
// R2 @88064: zi [u][64]; R3 @120832: hl stash [b][HPITCH] / cw [u][64].
// ---------------------------------------------------------------------------
template<bool PERSIST>
__device__ __forceinline__
void cell_body(int d, int rc, int bh, unsigned short* lds,
               const unsigned short* __restrict__ xt, const float* __restrict__ bfused,
               const unsigned short* __restrict__ wp1, const unsigned short* __restrict__ wp2,
               float* __restrict__ ring, float* __restrict__ out,
               ushort4v hl_st[2], f32x4 hl_zf[4]) {
  const int l = d - rc;
  const int tid = threadIdx.x;
  const int wave = tid >> 6, lane = tid & 63;
  const int quad = lane >> 4, l15 = lane & 15;
  float* R1 = (float*)((char*)lds + 54272);
  float* R2 = (float*)((char*)lds + 88064);
  float* R3 = (float*)((char*)lds + 120832);

  const bool vt = (l >= 1), vlft = (rc >= 1), vdg = vt && vlft;
  const float* slot1 = ring + (size_t)(((d + RING_D - 1) % RING_D) * 80) * 16384; // d-1
  const float* slot2 = ring + (size_t)(((d + RING_D - 2) % RING_D) * 80) * 16384; // d-2
  float* slotw = ring + ((size_t)((d % RING_D) * 80 + rc)) * 16384;
  const float* htopP  = slot1 + (size_t)rc * 16384;
  const float* hleftP = slot1 + (size_t)(rc - 1) * 16384;
  const float* hdiagP = slot2 + (size_t)(rc - 1) * 16384;

  // ---- stage q = [h_top | h_left | h_diag | s_ij] into LDS as bf16 ----
  const int idx0 = tid, idx1 = 1024 + tid;
  const int b0 = idx0 >> 5, c40 = (idx0 & 31) << 2;
  const int b1 = idx1 >> 5, c41 = (idx1 & 31) << 2;

  f32x4 hlg[2];
  hlg[0] = (f32x4){0.f, 0.f, 0.f, 0.f};
  hlg[1] = (f32x4){0.f, 0.f, 0.f, 0.f};
  if (PERSIST && vlft) {                 // issue IC loads first (latency overlap)
    ic_load4_issue(hleftP + bh * 8192 + b0 * 128 + c40, hlg[0]);
    ic_load4_issue(hleftP + bh * 8192 + b1 * 128 + c41, hlg[1]);
  }
  {
    const unsigned short* src = xt + (size_t)(l * 80 + rc) * 4096 + bh * 2048;
    int idx = tid * 2;                           // idx = b_local*32 + c
    int b = idx >> 5, c = idx & 31;
    *(ushort2v*)(lds + (size_t)b * QPITCH + 384 + c) = *(const ushort2v*)(src + idx);
  }
#pragma unroll
  for (int it = 0; it < 2; ++it) {
    int b = it ? b1 : b0, c4 = it ? c41 : c40;
    unsigned short* row = lds + (size_t)b * QPITCH;
    // h_top
    ushort4v ot = (ushort4v){0, 0, 0, 0};
    if (vt) {
      f32x4 v;
      if (PERSIST) v = *(const f32x4*)(R1 + b * HPITCH + c4);   // h_copy (LDS)
      else { float4 t4 = *(const float4*)(htopP + bh * 8192 + b * 128 + c4);
             v = (f32x4){t4.x, t4.y, t4.z, t4.w}; }
      ot = (ushort4v){f2bf(v[0]), f2bf(v[1]), f2bf(v[2]), f2bf(v[3])};
    }
    *(ushort4v*)(row + c4) = ot;
    // h_diag
    ushort4v od = (ushort4v){0, 0, 0, 0};
    if (vdg) {
      if (PERSIST) od = hl_st[it];
      else {
        float4 v = *(const float4*)(hdiagP + bh * 8192 + b * 128 + c4);
        od = (ushort4v){f2bf(v.x), f2bf(v.y), f2bf(v.z), f2bf(v.w)};
      }
    }
    *(ushort4v*)(row + 256 + c4) = od;
  }
  // h_left: wait for IC loads, convert, stash fp32 for z-fold
  if (PERSIST) {
    ic_wait2(hlg[0], hlg[1]);
#pragma unroll
    for (int it = 0; it < 2; ++it) {
      int b = it ? b1 : b0, c4 = it ? c41 : c40;
      f32x4 v = hlg[it];
      ushort4v ol = (ushort4v){f2bf(v[0]), f2bf(v[1]), f2bf(v[2]), f2bf(v[3])};
      *(ushort4v*)(lds + (size_t)b * QPITCH + 128 + c4) = ol;
      *(f32x4*)(R3 + b * HPITCH + c4) = v;
      hl_st[it] = ol;
    }
  } else {
#pragma unroll
    for (int it = 0; it < 2; ++it) {
      int b = it ? b1 : b0, c4 = it ? c41 : c40;
      ushort4v ol = (ushort4v){0, 0, 0, 0};
      if (vlft) {
        float4 v = *(const float4*)(hleftP + bh * 8192 + b * 128 + c4);
        ol = (ushort4v){f2bf(v.x), f2bf(v.y), f2bf(v.z), f2bf(v.w)};
      }
      *(ushort4v*)(lds + (size_t)b * QPITCH + 128 + c4) = ol;
    }
  }
  __syncthreads();                                             // S2

  // ---- GEMM1: fused [r|z|wij]^T = W' @ q^T, wave tile 64n x 64b ----
  f32x4 acc[4][4];
#pragma unroll
  for (int mt = 0; mt < 4; ++mt)
#pragma unroll
    for (int bt = 0; bt < 4; ++bt) acc[mt][bt] = (f32x4){0.f, 0.f, 0.f, 0.f};

  const int ntb = wave * 4;
  const int kb0 = (wave >= 14) ? 12 : 0;   // wij rows are zero for k < 384
  for (int kb = kb0; kb < 13; ++kb) {
    bf16x8 wf[4], qf[4];
#pragma unroll
    for (int mt = 0; mt < 4; ++mt)
      wf[mt] = *(const bf16x8*)(wp1 + ((size_t)(kb * 64 + ntb + mt) * 64 + lane) * 8);
#pragma unroll
    for (int bt = 0; bt < 4; ++bt)
      qf[bt] = *(const bf16x8*)(lds + (size_t)(bt * 16 + l15) * QPITCH + kb * 32 + quad * 8);
#pragma unroll
    for (int mt = 0; mt < 4; ++mt)
#pragma unroll
      for (int bt = 0; bt < 4; ++bt)
        acc[mt][bt] = __builtin_amdgcn_mfma_f32_16x16x32_bf16(wf[mt], qf[bt], acc[mt][bt], 0, 0, 0);
  }
  __syncthreads();                                             // S3

  // ---- phase 1: z waves read hl stash + h_top copy into regs (before the
  // epilogue overwrites those LDS regions); r class does its q RMW here too.
  const int u4 = (wave >= 6 && wave < 14) ? (wave - 6) * 16 + quad * 4 : 0;
  f32x4 hl4s[4], ht4s[4];
  if (wave >= 6 && wave < 14) {
#pragma unroll
    for (int bt = 0; bt < 4; ++bt) {
      int bl = bt * 16 + l15;
      hl4s[bt] = (f32x4){0.f, 0.f, 0.f, 0.f};
      ht4s[bt] = (f32x4){0.f, 0.f, 0.f, 0.f};
      if (PERSIST) {
        if (vlft) hl4s[bt] = *(const f32x4*)(R3 + bl * HPITCH + u4);
        if (vt)   ht4s[bt] = *(const f32x4*)(R1 + bl * HPITCH + u4);
      } else {
        int bg = bh * 64 + bl;
        if (vlft) { float4 v = *(const float4*)(hleftP + (size_t)bg * 128 + u4);
                    hl4s[bt] = (f32x4){v.x, v.y, v.z, v.w}; }
        if (vt)   { float4 v = *(const float4*)(htopP + (size_t)bg * 128 + u4);
                    ht4s[bt] = (f32x4){v.x, v.y, v.z, v.w}; }
      }
    }
  }
  if (wave < 6) {
    // ---- r class: sigmoid, then A2' = r*q in place in LDS ----
    const int rn0 = wave * 64;
    const int shift = (rn0 < 128) ? 128 : (rn0 < 256 ? -128 : 0);
#pragma unroll
    for (int mt = 0; mt < 4; ++mt)
#pragma unroll
      for (int bt = 0; bt < 4; ++bt) {
        int n0 = rn0 + mt * 16 + quad * 4;
        int row = bt * 16 + l15;
        unsigned short* p = lds + (size_t)row * QPITCH + n0 + shift;
        ushort4v qv = *(ushort4v*)p;
        f32x4 bf = *(const f32x4*)(bfused + n0);
        ushort4v o;
#pragma unroll
        for (int g = 0; g < 4; ++g) {
          float r = sigm(acc[mt][bt][g] + bf[g]);
          o[g] = f2bf(bf2f(qv[g]) * r);
        }
        *(ushort4v*)p = o;
      }
  }
  __syncthreads();                                             // S4

  // ---- phase 2 epilogue writes ----
  if (wave >= 6 && wave < 14) {
    // z class: lane-local softmax over 4 gates; fold h's
#pragma unroll
    for (int bt = 0; bt < 4; ++bt) {
      int bl = bt * 16 + l15;
      f32x4 hd4 = (f32x4){0.f, 0.f, 0.f, 0.f};
      if (vdg) {
        if (PERSIST) hd4 = hl_zf[bt];
        else { int bg = bh * 64 + bl;
               float4 v = *(const float4*)(hdiagP + (size_t)bg * 128 + u4);
               hd4 = (f32x4){v.x, v.y, v.z, v.w}; }
      }
      if (PERSIST) hl_zf[bt] = hl4s[bt];
#pragma unroll
      for (int mt = 0; mt < 4; ++mt) {
        int nb = wave * 64 + mt * 16 + quad * 4;
        f32x4 bf = *(const f32x4*)(bfused + nb);
        float v0 = acc[mt][bt][0] + bf[0];
        float v1 = acc[mt][bt][1] + bf[1];
        float v2 = acc[mt][bt][2] + bf[2];
        float v3 = acc[mt][bt][3] + bf[3];
        float m = fmaxf(fmaxf(v0, v1), fmaxf(v2, v3));
        float e0 = __expf(v0 - m), e1 = __expf(v1 - m);
        float e2 = __expf(v2 - m), e3 = __expf(v3 - m);
        float inv = 1.f / (e0 + e1 + e2 + e3);
        int u = u4 + mt;
        R1[u * 64 + bl] = (e1 * hl4s[bt][mt] + e2 * ht4s[bt][mt] + e3 * hd4[mt]) * inv;
        R2[u * 64 + bl] = e0 * inv;
      }
    }
  } else if (wave >= 14) {
    // wij class: cw = acc + bij
#pragma unroll
    for (int mt = 0; mt < 4; ++mt)
#pragma unroll
      for (int bt = 0; bt < 4; ++bt) {
        int n0 = wave * 64 + mt * 16 + quad * 4;
        int uw = n0 - 896;
        int bl = bt * 16 + l15;
        f32x4 bf = *(const f32x4*)(bfused + n0);
#pragma unroll
        for (int g = 0; g < 4; ++g)
          R3[(uw + g) * 64 + bl] = acc[mt][bt][g] + bf[g];
      }
  }
  __syncthreads();                                             // S5

  // ---- GEMM2: hU^T = WU' @ A2'^T (M=128 u, K=384, N=64 bl) ----
  const int m2 = wave >> 1, bsel = wave & 1;
  f32x4 acc2[2];
  acc2[0] = (f32x4){0.f, 0.f, 0.f, 0.f};
  acc2[1] = (f32x4){0.f, 0.f, 0.f, 0.f};
  for (int kb = 0; kb < 12; ++kb) {
    bf16x8 wf = *(const bf16x8*)(wp2 + ((size_t)(kb * 8 + m2) * 64 + lane) * 8);
    bf16x8 q0 = *(const bf16x8*)(lds + (size_t)((bsel * 2 + 0) * 16 + l15) * QPITCH + kb * 32 + quad * 8);
    bf16x8 q1 = *(const bf16x8*)(lds + (size_t)((bsel * 2 + 1) * 16 + l15) * QPITCH + kb * 32 + quad * 8);
    acc2[0] = __builtin_amdgcn_mfma_f32_16x16x32_bf16(wf, q0, acc2[0], 0, 0, 0);
    acc2[1] = __builtin_amdgcn_mfma_f32_16x16x32_bf16(wf, q1, acc2[1], 0, 0, 0);
  }

  // ---- combine: h = hz + zi * tanh(cw + hU) ----
  f32x4 hout[2];
#pragma unroll
  for (int bt = 0; bt < 2; ++bt) {
    int bl = (bsel * 2 + bt) * 16 + l15;
    int u0 = m2 * 16 + quad * 4;
#pragma unroll
    for (int g = 0; g < 4; ++g) {
      float cw  = R3[(u0 + g) * 64 + bl];
      float hzv = R1[(u0 + g) * 64 + bl];
      float ziv = R2[(u0 + g) * 64 + bl];
      hout[bt][g] = hzv + ziv * tanh_fast(cw + acc2[bt][g]);
    }
  }
  __syncthreads();                                             // S6
#pragma unroll
  for (int bt = 0; bt < 2; ++bt) {
    int bl = (bsel * 2 + bt) * 16 + l15;
    int u0 = m2 * 16 + quad * 4;
    float* dst = slotw + (size_t)(bh * 64 + bl) * 128 + u0;
    if (PERSIST) {
      *(f32x4*)(R1 + bl * HPITCH + u0) = hout[bt];   // h_copy for next step
      ic_store4(dst, hout[bt]);
    } else {
      *(f32x4*)dst = hout[bt];
    }
    if (d == 158) *(f32x4*)(out + (size_t)(bh * 64 + bl) * 128 + u0) = hout[bt];
  }
}

// ---------------------------------------------------------------------------
__global__ __launch_bounds__(1024)
void gru_coop(const unsigned short* __restrict__ xt, const float* __restrict__ bfused,
              const unsigned short* __restrict__ wp1, const unsigned short* __restrict__ wp2,
              float* __restrict__ ring, float* __restrict__ out,
              unsigned int* __restrict__ done) {
  extern __shared__ unsigned short lds[];
  const int blk = blockIdx.x;
  const int rc = (blk < 80) ? blk : blk - 80;
  const int bh = (blk < 80) ? 0 : 1;
  const int tid = threadIdx.x;
  ushort4v hl_st[2] = {(ushort4v){0,0,0,0}, (ushort4v){0,0,0,0}};
  f32x4 hl_zf[4];
#pragma unroll
  for (int i = 0; i < 4; ++i) hl_zf[i] = (f32x4){0.f, 0.f, 0.f, 0.f};

  for (int d = 0; d < 159; ++d) {
    const int l = d - rc;
    const bool active = (l >= 0 && l < 80);
    if (active && d > 0 && tid == 0) {
      int spin = 0;
      // data dep: left neighbor finished step d-1
      if (rc >= 1)
        while ((int)__hip_atomic_load(&done[blk - 1], __ATOMIC_RELAXED,
                                      __HIP_MEMORY_SCOPE_AGENT) < d) {
          if (spin < 128) { __builtin_amdgcn_s_sleep(1); ++spin; }
          else __builtin_amdgcn_s_sleep(4);
        }
      // ring-slot reuse: right neighbor past step d-(RING_D-2)
      if (rc <= 78) {
        int need = d - (RING_D - 2);
        if (need > 0)
          while ((int)__hip_atomic_load(&done[blk + 1], __ATOMIC_RELAXED,
                                        __HIP_MEMORY_SCOPE_AGENT) < need)
            __builtin_amdgcn_s_sleep(4);
      }
    }
    __syncthreads();                                           // S1
    if (active)
      cell_body<true>(d, rc, bh, lds, xt, bfused, wp1, wp2, ring, out, hl_st, hl_zf);
    asm volatile("s_waitcnt vmcnt(0)" ::: "memory");
    __syncthreads();                                           // S7
    if (tid == 0)
      __hip_atomic_store(&done[blk], (unsigned)(d + 1), __ATOMIC_RELAXED,
                         __HIP_MEMORY_SCOPE_AGENT);
  }
}

// Fallback (coop launch rejected): one launch per diagonal, ring mode.
__global__ __launch_bounds__(1024)
void gru_step(int d, const unsigned short* __restrict__ xt, const float* __restrict__ bfused,
              const unsigned short* __restrict__ wp1, const unsigned short* __restrict__ wp2,
              float* __restrict__ ring, float* __restrict__ out) {
  extern __shared__ unsigned short lds[];
  const int blk = blockIdx.x;
  const int rc = (blk < 80) ? blk : blk - 80;
  const int bh = (blk < 80) ? 0 : 1;
  const int l = d - rc;
  ushort4v hl_st[2]; f32x4 hl_zf[4];
  if (l >= 0 && l < 80)
    cell_body<false>(d, rc, bh, lds, xt, bfused, wp1, wp2, ring, out, hl_st, hl_zf);
}

// ---------------------------------------------------------------------------
extern "C" void kernel_launch(void* const* d_in, const int* in_sizes, int n_in,
                              void* d_out, int out_size, void* d_ws, size_t ws_size,
                              hipStream_t stream) {
  const float* x   = (const float*)d_in[0];
  const float* Wr  = (const float*)d_in[1];
  const float* br  = (const float*)d_in[2];
  const float* Wz  = (const float*)d_in[3];
  const float* bz  = (const float*)d_in[4];
  const float* Wij = (const float*)d_in[5];
  const float* bij = (const float*)d_in[6];
  const float* WU  = (const float*)d_in[7];
  float* out = (float*)d_out;

  // ws layout (~95.3 MB)
  char* ws = (char*)d_ws;
  unsigned short* wp1 = (unsigned short*)(ws);                  //    851,968 B
  unsigned short* wp2 = (unsigned short*)(ws + 851968);         //     98,304 B
  float* bfused       = (float*)(ws + 950272);                  //      4,096 B
  float* ring         = (float*)(ws + 954368);                  // 41,943,040 B (8 slots)
  unsigned short* xt  = (unsigned short*)(ws + 42897408);       // 52,428,800 B
  unsigned int* done  = (unsigned int*)(ws + 95326208);         //      1,024 B

  (void)hipFuncSetAttribute((const void*)gru_coop,
                            hipFuncAttributeMaxDynamicSharedMemorySize, LDS_BYTES);
  (void)hipFuncSetAttribute((const void*)gru_step,
                            hipFuncAttributeMaxDynamicSharedMemorySize, LDS_BYTES);

  prep_kernel<<<929, 64, 0, stream>>>(Wr, Wz, Wij, WU, br, bz, bij, wp1, wp2, bfused);
  transpose_kernel<<<5120, 256, 0, stream>>>(x, xt);
  zero_arr<<<1, 256, 0, stream>>>(done);

  const unsigned short* xt_c = xt;
  const float* bf_c = bfused;
  const unsigned short* wp1_c = wp1;
  const unsigned short* wp2_c = wp2;
  float* ring_l = ring;
  float* out_l = out;
  unsigned int* done_l = done;
  void* args[] = {(void*)&xt_c, (void*)&bf_c, (void*)&wp1_c, (void*)&wp2_c,
                  (void*)&ring_l, (void*)&out_l, (void*)&done_l};
  hipError_t e = hipLaunchCooperativeKernel((const void*)gru_coop, dim3(160), dim3(1024),
                                            args, LDS_BYTES, stream);
  if (e != hipSuccess) {
    for (int d = 0; d < 159; ++d)
      gru_step<<<160, 1024, LDS_BYTES, stream>>>(d, xt, bfused, wp1, wp2, ring, out);
  }
}